// Round 2
// baseline (1404.846 us; speedup 1.0000x reference)
//
#include <hip/hip_runtime.h>
#include <hip/hip_bf16.h>

#define SEQ 512
#define HID 768
#define HEADS 12
#define DH 64
#define LAYERS 12
#define BATCH 32
#define TOK (BATCH*SEQ)   // 16384
#define NPH (BATCH*DH)    // 2048: per-head N dimension of the mix GEMM

typedef __attribute__((ext_vector_type(8))) __bf16 bf16x8;
typedef __attribute__((ext_vector_type(4))) __bf16 bf16x4;
typedef __attribute__((ext_vector_type(4))) float f32x4;

typedef __attribute__((address_space(1))) const void gvoid;
typedef __attribute__((address_space(3))) void svoid;
// async global->LDS, 16B/lane; LDS dest must be wave-uniform base + lane*16 [m97/m104]
__device__ __forceinline__ void async_cp16(const void* g, void* l) {
  __builtin_amdgcn_global_load_lds((gvoid*)g, (svoid*)l, 16, 0, 0);
}

#define SB   __builtin_amdgcn_s_barrier()
#define FENCE asm volatile("" ::: "memory")
#define LGKM0 do { asm volatile("s_waitcnt lgkmcnt(0)" ::: "memory"); \
                   __builtin_amdgcn_sched_barrier(0); } while (0)

// ---------------- fp32 -> bf16 bulk convert (W, last_w) ----------------
__global__ __launch_bounds__(256) void convert_k(
    const float* __restrict__ src, __bf16* __restrict__ dst) {
  int i = (blockIdx.x * 256 + threadIdx.x) * 4;
  f32x4 v = *(const f32x4*)&src[i];
  bf16x4 b;
#pragma unroll
  for (int j = 0; j < 4; j++) b[j] = (__bf16)v[j];
  *(bf16x4*)&dst[i] = b;
}

// ---------------- embed + layernorm: fp32 in -> bf16 h[tok][c] ----------------
__global__ __launch_bounds__(256) void embed_ln_k(
    const int* __restrict__ x, const float* __restrict__ we,
    const float* __restrict__ pe, const float* __restrict__ te,
    const float* __restrict__ g, const float* __restrict__ be,
    __bf16* __restrict__ h) {
  const int tok = blockIdx.x;
  const int s = tok & (SEQ - 1);
  const int wid = x[tok];
  const int tid = threadIdx.x;
  float v[3];
  float sum = 0.f, sq = 0.f;
#pragma unroll
  for (int j = 0; j < 3; j++) {
    int c = tid + j * 256;
    float val = we[(size_t)wid * HID + c] + pe[(size_t)s * HID + c] + te[c];
    v[j] = val; sum += val; sq += val * val;
  }
#pragma unroll
  for (int off = 32; off > 0; off >>= 1) {
    sum += __shfl_down(sum, off);
    sq  += __shfl_down(sq, off);
  }
  __shared__ float rs_[4], rq_[4];
  const int wv = tid >> 6;
  if ((tid & 63) == 0) { rs_[wv] = sum; rq_[wv] = sq; }
  __syncthreads();
  sum = rs_[0] + rs_[1] + rs_[2] + rs_[3];
  sq  = rq_[0] + rq_[1] + rq_[2] + rq_[3];
  const float mu  = sum * (1.f / HID);
  const float var = sq * (1.f / HID) - mu * mu;
  const float inv = rsqrtf(var + 1e-12f);
#pragma unroll
  for (int j = 0; j < 3; j++) {
    int c = tid + j * 256;
    float o = (v[j] - mu) * inv * g[c] + be[c];
    h[(size_t)tok * HID + c] = (__bf16)o;
  }
}

// ---------------- all-layer M transpose+convert: Mt[l][h][t][s] = bf16(M[l][h][s][t]) ----------------
__global__ __launch_bounds__(256) void transpose_all_m_k(
    const float* __restrict__ M, __bf16* __restrict__ Mt) {
  __shared__ float tile[64][68];            // +4 pad
  const int lh = blockIdx.z;                // layer*HEADS + head
  const int t0 = blockIdx.x * 64, s0 = blockIdx.y * 64;
  const float* src = M + (size_t)lh * SEQ * SEQ;
  __bf16* dst = Mt + (size_t)lh * SEQ * SEQ;
  const int tid = threadIdx.x;
#pragma unroll
  for (int it = 0; it < 4; it++) {
    int e = (it * 256 + tid) * 4;
    int r = e >> 6, c = e & 63;             // tile[r=s][c=t]
    *(f32x4*)&tile[r][c] = *(const f32x4*)&src[(size_t)(s0 + r) * SEQ + t0 + c];
  }
  __syncthreads();
#pragma unroll
  for (int it = 0; it < 2; it++) {
    int e = (it * 256 + tid) * 8;
    int r = e >> 6, c = e & 63;
    bf16x8 vv;
#pragma unroll
    for (int j = 0; j < 8; j++) vv[j] = (__bf16)tile[c + j][r];
    *(bf16x8*)&dst[(size_t)(t0 + r) * SEQ + s0 + c] = vv;
  }
}

// =====================================================================
// 256x256 / BK=64 8-phase GEMM (T2 swizzle + T3/T4 counted vmcnt + T5).
// C[m][n] = sum_k A[m][k] * B[n][k]  (both row-major over K, ld == K).
// 8 waves as 2(M)x4(N); wave computes 128x64.  Per K-tile: 4 phases x 16 MFMA.
// LDS: 2 dbuf x 2 halves x [128][64] bf16 per operand = 128 KiB total.
// Phase schedule per K-tile window Tj:
//   p1: read aA(12 w/ b0) ; stage T(j+1).hB0 ; MFMA Q0 (mi0-3 x ni0-1)
//   p2: read aB(8)        ; stage T(j+1).hB1 ; MFMA Q1 (mi4-7 x ni0-1)
//   p3: read b1(4)        ; stage T(j+2).hA0 ; MFMA Q2 (mi0-3 x ni2-3)
//   p4:                    stage T(j+2).hA1 ; MFMA Q3 (mi4-7 x ni2-3)
//       then s_waitcnt vmcnt(4) (forces T(j+1) fully landed; 2 newest
//       half-tiles may stay in flight) ; barrier.
// Restage safety: A-halves die at p2 (last ds_read), restaged p3/p4;
// B-halves die at p3, restaged next-window p1/p2 — always >=1 barrier apart.
// T2 st_16x32: linear LDS dest, inverse-swizzled global src col, XOR on read.
// MODE 0: dense  -> X[h][b*64+d][s] scatter (bf16)
// MODE 1: mix    -> relu(acc+bias) -> hout[b][t][h*64+d] (bf16)
// MODE 2: final  -> acc+bias -> out[tok][dout] (fp32)
// =====================================================================
template <int MODE>
__global__ __launch_bounds__(512, 2) void gemm256_k(
    const __bf16* __restrict__ Abase, const __bf16* __restrict__ Bbase,
    const float* __restrict__ bias, void* __restrict__ Cout, int K) {
  __shared__ __bf16 LA[2][2][128 * 64];
  __shared__ __bf16 LB[2][2][128 * 64];
  const int tid = threadIdx.x;
  const int w = tid >> 6, lane = tid & 63;
  const int lm = lane & 15, q = lane >> 4;
  const int srow = lane >> 3;                                  // staging row within 8-group
  const int scol = ((lane & 7) * 8) ^ ((lane & 32) ? 16 : 0);  // pre-swizzled src col (elems)
  const int axor = (lm & 4) ? 16 : 0;                          // read-side swizzle (elems)
  const int haA = w >> 2;                                      // this wave's A half
  const int hbB = (w & 3) >> 1;                                // this wave's B half
  const int rB0 = (w & 1) * 64;                                // row base within B half
  const int m0 = blockIdx.x * 256, n0 = blockIdx.y * 256;
  const __bf16* A = Abase;
  const __bf16* B = Bbase;
  int head = 0;
  if constexpr (MODE == 1) {
    head = blockIdx.z;
    A += (size_t)head * SEQ * SEQ;
    B += (size_t)head * (NPH * SEQ);
  }

  // stage half-tile (jt, h) of A (isB=0) or B (isB=1): 16 KB, 2 loads/lane
  auto STAGE = [&](int jt, int h, int isB) {
    const __bf16* src = isB ? B : A;
    const int r0 = (isB ? n0 : m0) + h * 128 + w * 16 + srow;
    const int kc = jt * 64 + scol;
    __bf16* lds = (isB ? &LB[jt & 1][h][0] : &LA[jt & 1][h][0]) + w * 1024 + lane * 8;
    async_cp16(&src[(size_t)r0 * K + kc], lds);
    async_cp16(&src[(size_t)(r0 + 8) * K + kc], lds + 512);
  };

  f32x4 acc[8][4];
#pragma unroll
  for (int i = 0; i < 8; i++)
#pragma unroll
    for (int j = 0; j < 4; j++) acc[i][j] = {0.f, 0.f, 0.f, 0.f};

  const int NT = K >> 6;
  // ---- prologue: T0 (4 halves) + T1.hA0/hA1; gate; barrier
  STAGE(0, 0, 0); STAGE(0, 1, 0);
  STAGE(0, 0, 1); STAGE(0, 1, 1);
  STAGE(1, 0, 0); STAGE(1, 1, 0);
  asm volatile("s_waitcnt vmcnt(4)" ::: "memory");
  SB; FENCE;

  for (int j = 0; j < NT; ++j) {
    const __bf16* lA = &LA[j & 1][haA][0];
    const __bf16* lB = &LB[j & 1][hbB][0];
    bf16x8 aA[4][2], aB[4][2], b0[2][2], b1[2][2];
    // ---------- p1 ----------
#pragma unroll
    for (int mi = 0; mi < 4; mi++)
#pragma unroll
      for (int ks = 0; ks < 2; ks++)
        aA[mi][ks] = *(const bf16x8*)&lA[((mi * 16 + lm) * 64 + ks * 32 + q * 8) ^ axor];
#pragma unroll
    for (int nn = 0; nn < 2; nn++)
#pragma unroll
      for (int ks = 0; ks < 2; ks++)
        b0[nn][ks] = *(const bf16x8*)&lB[((rB0 + nn * 16 + lm) * 64 + ks * 32 + q * 8) ^ axor];
    if (j + 1 < NT) STAGE(j + 1, 0, 1);
    SB; LGKM0;
    __builtin_amdgcn_s_setprio(1);
#pragma unroll
    for (int mi = 0; mi < 4; mi++)
#pragma unroll
      for (int nn = 0; nn < 2; nn++)
#pragma unroll
        for (int ks = 0; ks < 2; ks++)
          acc[mi][nn] = __builtin_amdgcn_mfma_f32_16x16x32_bf16(aA[mi][ks], b0[nn][ks], acc[mi][nn], 0, 0, 0);
    __builtin_amdgcn_s_setprio(0);
    SB; FENCE;
    // ---------- p2 ----------
#pragma unroll
    for (int mi = 0; mi < 4; mi++)
#pragma unroll
      for (int ks = 0; ks < 2; ks++)
        aB[mi][ks] = *(const bf16x8*)&lA[(((mi + 4) * 16 + lm) * 64 + ks * 32 + q * 8) ^ axor];
    if (j + 1 < NT) STAGE(j + 1, 1, 1);
    SB; LGKM0;
    __builtin_amdgcn_s_setprio(1);
#pragma unroll
    for (int mi = 0; mi < 4; mi++)
#pragma unroll
      for (int nn = 0; nn < 2; nn++)
#pragma unroll
        for (int ks = 0; ks < 2; ks++)
          acc[mi + 4][nn] = __builtin_amdgcn_mfma_f32_16x16x32_bf16(aB[mi][ks], b0[nn][ks], acc[mi + 4][nn], 0, 0, 0);
    __builtin_amdgcn_s_setprio(0);
    SB; FENCE;
    // ---------- p3 ----------
#pragma unroll
    for (int nn = 0; nn < 2; nn++)
#pragma unroll
      for (int ks = 0; ks < 2; ks++)
        b1[nn][ks] = *(const bf16x8*)&lB[((rB0 + (nn + 2) * 16 + lm) * 64 + ks * 32 + q * 8) ^ axor];
    if (j + 2 < NT) STAGE(j + 2, 0, 0);
    SB; LGKM0;
    __builtin_amdgcn_s_setprio(1);
#pragma unroll
    for (int mi = 0; mi < 4; mi++)
#pragma unroll
      for (int nn = 0; nn < 2; nn++)
#pragma unroll
        for (int ks = 0; ks < 2; ks++)
          acc[mi][nn + 2] = __builtin_amdgcn_mfma_f32_16x16x32_bf16(aA[mi][ks], b1[nn][ks], acc[mi][nn + 2], 0, 0, 0);
    __builtin_amdgcn_s_setprio(0);
    SB; FENCE;
    // ---------- p4 (no mid-barrier: no new reads) ----------
    if (j + 2 < NT) STAGE(j + 2, 1, 0);
    __builtin_amdgcn_s_setprio(1);
#pragma unroll
    for (int mi = 0; mi < 4; mi++)
#pragma unroll
      for (int nn = 0; nn < 2; nn++)
#pragma unroll
        for (int ks = 0; ks < 2; ks++)
          acc[mi + 4][nn + 2] = __builtin_amdgcn_mfma_f32_16x16x32_bf16(aB[mi][ks], b1[nn][ks], acc[mi + 4][nn + 2], 0, 0, 0);
    __builtin_amdgcn_s_setprio(0);
    if (j + 2 < NT) { asm volatile("s_waitcnt vmcnt(4)" ::: "memory"); }
    else            { asm volatile("s_waitcnt vmcnt(0)" ::: "memory"); }
    SB; FENCE;
  }

  // ---- epilogue.  D frag layout: row(m)=q*4+r, col(n)=lm  [m89/m91]
#pragma unroll
  for (int mi = 0; mi < 8; mi++)
#pragma unroll
    for (int ni = 0; ni < 4; ni++)
#pragma unroll
      for (int r = 0; r < 4; r++) {
        const int row = m0 + (w >> 2) * 128 + mi * 16 + q * 4 + r;
        const int col = n0 + (w & 3) * 64 + ni * 16 + lm;
        const float v = acc[mi][ni][r];
        if constexpr (MODE == 0) {
          const int hh = row >> 6, dd = row & 63;
          const int bb2 = col >> 9, ss = col & (SEQ - 1);
          ((__bf16*)Cout)[(size_t)hh * (NPH * SEQ) + (size_t)bb2 * (DH * SEQ) +
                          (size_t)dd * SEQ + ss] = (__bf16)v;
        } else if constexpr (MODE == 1) {
          const int bb2 = col >> 6, dd = col & 63;
          const float vv = fmaxf(v + bias[head * DH + dd], 0.f);
          ((__bf16*)Cout)[((size_t)bb2 * SEQ + row) * HID + head * DH + dd] = (__bf16)vv;
        } else {
          ((float*)Cout)[(size_t)row * HID + col] = v + bias[col];
        }
      }
}

extern "C" void kernel_launch(void* const* d_in, const int* in_sizes, int n_in,
                              void* d_out, int out_size, void* d_ws, size_t ws_size,
                              hipStream_t stream) {
  const int*   x   = (const int*)d_in[0];
  const float* we  = (const float*)d_in[1];
  const float* pe  = (const float*)d_in[2];
  const float* te  = (const float*)d_in[3];
  const float* lng = (const float*)d_in[4];
  const float* lnb = (const float*)d_in[5];
  const float* W   = (const float*)d_in[6];   // [12][768][768] fp32
  const float* bb  = (const float*)d_in[7];   // [12][768] fp32
  const float* M   = (const float*)d_in[8];   // [12][12][512][512] fp32
  const float* lw  = (const float*)d_in[9];
  const float* lb  = (const float*)d_in[10];

  // workspace (bf16), ~141 MB total:
  __bf16* Mt  = (__bf16*)d_ws;                            // 12*12*512*512 = 75.5 MB
  __bf16* Wb  = Mt + (size_t)LAYERS * HEADS * SEQ * SEQ;  // 12*768*768    = 14.2 MB
  __bf16* lwb = Wb + (size_t)LAYERS * HID * HID;          // 768*768       = 1.2 MB
  __bf16* hA  = lwb + (size_t)HID * HID;                  // 16384*768     = 25.2 MB
  __bf16* X   = hA + (size_t)TOK * HID;                   // 12*2048*512   = 25.2 MB (per-head [2048][512])
  float* out = (float*)d_out;

  convert_k<<<LAYERS * HID * HID / 1024, 256, 0, stream>>>(W, Wb);
  convert_k<<<HID * HID / 1024, 256, 0, stream>>>(lw, lwb);
  transpose_all_m_k<<<dim3(8, 8, LAYERS * HEADS), 256, 0, stream>>>(M, Mt);
  embed_ln_k<<<TOK, 256, 0, stream>>>(x, we, pe, te, lng, lnb, hA);
  for (int l = 0; l < LAYERS; l++) {
    // dense: A = Wb[l] (m=dout over 768 -> 3 tiles), B = hA (n=tok -> 64 tiles)
    gemm256_k<0><<<dim3(3, 64), 512, 0, stream>>>(Wb + (size_t)l * HID * HID, hA,
                                                  nullptr, X, HID);
    // mix: per head, A = Mt[l][h] (m=t -> 2 tiles), B = X[h] (n=b*64+d -> 8 tiles)
    gemm256_k<1><<<dim3(2, 8, HEADS), 512, 0, stream>>>(Mt + (size_t)l * HEADS * SEQ * SEQ, X,
                                                        bb + (size_t)l * HID, hA, SEQ);
  }
  // final: A = hA (m=tok -> 64 tiles), B = lwb (n=dout -> 3 tiles), fp32 out
  gemm256_k<2><<<dim3(64, 3), 512, 0, stream>>>(hA, lwb, lb, out, HID);
}

// Round 3
// 1236.064 us; speedup vs baseline: 1.1365x; 1.1365x over previous
//
#include <hip/hip_runtime.h>
#include <hip/hip_bf16.h>

#define SEQ 512
#define HID 768
#define HEADS 12
#define DH 64
#define LAYERS 12
#define BATCH 32
#define TOK (BATCH*SEQ)   // 16384
#define NPH (BATCH*DH)    // 2048: per-head N dimension of the mix GEMM

typedef __attribute__((ext_vector_type(8))) __bf16 bf16x8;
typedef __attribute__((ext_vector_type(4))) __bf16 bf16x4;
typedef __attribute__((ext_vector_type(4))) float f32x4;

typedef __attribute__((address_space(1))) const void gvoid;
typedef __attribute__((address_space(3))) void svoid;
// async global->LDS, 16B/lane; LDS dest must be wave-uniform base + lane*16 [m97/m104]
__device__ __forceinline__ void async_cp16(const void* g, void* l) {
  __builtin_amdgcn_global_load_lds((gvoid*)g, (svoid*)l, 16, 0, 0);
}

#define SB   __builtin_amdgcn_s_barrier()
#define FENCE asm volatile("" ::: "memory")
#define LGKM0 do { asm volatile("s_waitcnt lgkmcnt(0)" ::: "memory"); \
                   __builtin_amdgcn_sched_barrier(0); } while (0)

// ---------------- fp32 -> bf16 bulk convert (W, last_w) ----------------
__global__ __launch_bounds__(256) void convert_k(
    const float* __restrict__ src, __bf16* __restrict__ dst) {
  int i = (blockIdx.x * 256 + threadIdx.x) * 4;
  f32x4 v = *(const f32x4*)&src[i];
  bf16x4 b;
#pragma unroll
  for (int j = 0; j < 4; j++) b[j] = (__bf16)v[j];
  *(bf16x4*)&dst[i] = b;
}

// ---------------- embed + layernorm: fp32 in -> bf16 h[tok][c] ----------------
__global__ __launch_bounds__(256) void embed_ln_k(
    const int* __restrict__ x, const float* __restrict__ we,
    const float* __restrict__ pe, const float* __restrict__ te,
    const float* __restrict__ g, const float* __restrict__ be,
    __bf16* __restrict__ h) {
  const int tok = blockIdx.x;
  const int s = tok & (SEQ - 1);
  const int wid = x[tok];
  const int tid = threadIdx.x;
  float v[3];
  float sum = 0.f, sq = 0.f;
#pragma unroll
  for (int j = 0; j < 3; j++) {
    int c = tid + j * 256;
    float val = we[(size_t)wid * HID + c] + pe[(size_t)s * HID + c] + te[c];
    v[j] = val; sum += val; sq += val * val;
  }
#pragma unroll
  for (int off = 32; off > 0; off >>= 1) {
    sum += __shfl_down(sum, off);
    sq  += __shfl_down(sq, off);
  }
  __shared__ float rs_[4], rq_[4];
  const int wv = tid >> 6;
  if ((tid & 63) == 0) { rs_[wv] = sum; rq_[wv] = sq; }
  __syncthreads();
  sum = rs_[0] + rs_[1] + rs_[2] + rs_[3];
  sq  = rq_[0] + rq_[1] + rq_[2] + rq_[3];
  const float mu  = sum * (1.f / HID);
  const float var = sq * (1.f / HID) - mu * mu;
  const float inv = rsqrtf(var + 1e-12f);
#pragma unroll
  for (int j = 0; j < 3; j++) {
    int c = tid + j * 256;
    float o = (v[j] - mu) * inv * g[c] + be[c];
    h[(size_t)tok * HID + c] = (__bf16)o;
  }
}

// ---------------- all-layer M transpose+convert: Mt[l][h][t][s] = bf16(M[l][h][s][t]) ----------------
__global__ __launch_bounds__(256) void transpose_all_m_k(
    const float* __restrict__ M, __bf16* __restrict__ Mt) {
  __shared__ float tile[64][68];            // +4 pad
  const int lh = blockIdx.z;                // layer*HEADS + head
  const int t0 = blockIdx.x * 64, s0 = blockIdx.y * 64;
  const float* src = M + (size_t)lh * SEQ * SEQ;
  __bf16* dst = Mt + (size_t)lh * SEQ * SEQ;
  const int tid = threadIdx.x;
#pragma unroll
  for (int it = 0; it < 4; it++) {
    int e = (it * 256 + tid) * 4;
    int r = e >> 6, c = e & 63;             // tile[r=s][c=t]
    *(f32x4*)&tile[r][c] = *(const f32x4*)&src[(size_t)(s0 + r) * SEQ + t0 + c];
  }
  __syncthreads();
#pragma unroll
  for (int it = 0; it < 2; it++) {
    int e = (it * 256 + tid) * 8;
    int r = e >> 6, c = e & 63;
    bf16x8 vv;
#pragma unroll
    for (int j = 0; j < 8; j++) vv[j] = (__bf16)tile[c + j][r];
    *(bf16x8*)&dst[(size_t)(t0 + r) * SEQ + s0 + c] = vv;
  }
}

// =====================================================================
// 256x256 / BK=64 8-phase GEMM (T2 swizzle + T3/T4 counted vmcnt + T5).
// C[m][n] = sum_k A[m][k] * B[n][k]  (both row-major over K, ld == K).
// 8 waves as 2(M)x4(N); wave computes 128x64.  Per K-tile: 4 phases x 16 MFMA.
// LDS: A double-buffered (64 KB), B TRIPLE-buffered (96 KB) = 160 KB.
// Window j (one K-tile):
//   p1: read aA+b0 ; stage T(j+2).hB0 ; MFMA Q0
//   p2: read aB    ; stage T(j+2).hB1 ; MFMA Q1
//   p3: read b1    ; stage T(j+2).hA0 ; MFMA Q2
//   p4:             stage T(j+2).hA1 ; MFMA Q3 ; vmcnt(8) ; barrier
// Gate vmcnt(8): leaves this window's 8 loads (T(j+2)) in flight, forces
// T(j+1) fully landed.  Stage->gate lead: B = 7 phases (~1100cy, covers
// HBM), A = 5 phases (covers L2/L3-resident operands, which A always is:
// Wb/Mt/hA are shared or LLC-hot).  Round-2's double-buffered B had only a
// 3-phase lead -> every window stalled at the gate (the 1405us regression).
// Buffer ledger: LB writes go to (j+2)%3, reads from j%3; (j+2)%3==(j-1)%3
// was last read at window j-1 p3 (drained by LGKM0, >=2 barriers before the
// stage issue).  LA parity reuse: stage at p3/p4 lands after p2's last read
// of the same region (reads drained before p2's closing barrier).
// T2 st_16x32: linear LDS dest, inverse-swizzled global src col, XOR on read.
// MODE 0: dense  -> X[h][b*64+d][s] scatter (bf16)
// MODE 1: mix    -> relu(acc+bias) -> hout[b][t][h*64+d] (bf16)
// MODE 2: final  -> acc+bias -> out[tok][dout] (fp32)
// =====================================================================
template <int MODE>
__global__ __launch_bounds__(512, 2) void gemm256_k(
    const __bf16* __restrict__ Abase, const __bf16* __restrict__ Bbase,
    const float* __restrict__ bias, void* __restrict__ Cout, int K) {
  __shared__ __bf16 LA[2][2][128 * 64];     // 64 KB
  __shared__ __bf16 LB[3][2][128 * 64];     // 96 KB
  const int tid = threadIdx.x;
  const int w = tid >> 6, lane = tid & 63;
  const int lm = lane & 15, q = lane >> 4;
  const int srow = lane >> 3;                                  // staging row within 8-group
  const int scol = ((lane & 7) * 8) ^ ((lane & 32) ? 16 : 0);  // pre-swizzled src col (elems)
  const int axor = (lm & 4) ? 16 : 0;                          // read-side swizzle (elems)
  const int haA = w >> 2;                                      // this wave's A half
  const int hbB = (w & 3) >> 1;                                // this wave's B half
  const int rB0 = (w & 1) * 64;                                // row base within B half
  const int m0 = blockIdx.x * 256, n0 = blockIdx.y * 256;
  const __bf16* A = Abase;
  const __bf16* B = Bbase;
  int head = 0;
  if constexpr (MODE == 1) {
    head = blockIdx.z;
    A += (size_t)head * SEQ * SEQ;
    B += (size_t)head * (NPH * SEQ);
  }

  // stage half-tile (jt, h) of A (isB=0, buffer jt&1) or B (isB=1, buffer jt%3)
  auto STAGE = [&](int jt, int h, int isB) {
    const __bf16* src = isB ? B : A;
    const int r0 = (isB ? n0 : m0) + h * 128 + w * 16 + srow;
    const int kc = jt * 64 + scol;
    __bf16* lds = (isB ? &LB[jt % 3][h][0] : &LA[jt & 1][h][0]) + w * 1024 + lane * 8;
    async_cp16(&src[(size_t)r0 * K + kc], lds);
    async_cp16(&src[(size_t)(r0 + 8) * K + kc], lds + 512);
  };

  f32x4 acc[8][4];
#pragma unroll
  for (int i = 0; i < 8; i++)
#pragma unroll
    for (int j = 0; j < 4; j++) acc[i][j] = {0.f, 0.f, 0.f, 0.f};

  const int NT = K >> 6;
  // ---- prologue: T0 (4 halves) + T1 (4 halves); force T0; barrier
  STAGE(0, 0, 0); STAGE(0, 1, 0); STAGE(0, 0, 1); STAGE(0, 1, 1);
  STAGE(1, 0, 0); STAGE(1, 1, 0); STAGE(1, 0, 1); STAGE(1, 1, 1);
  asm volatile("s_waitcnt vmcnt(8)" ::: "memory");
  SB; FENCE;

  for (int j = 0; j < NT; ++j) {
    const __bf16* lA = &LA[j & 1][haA][0];
    const __bf16* lB = &LB[j % 3][hbB][0];
    bf16x8 aA[4][2], aB[4][2], b0[2][2], b1[2][2];
    // ---------- p1 ----------
#pragma unroll
    for (int mi = 0; mi < 4; mi++)
#pragma unroll
      for (int ks = 0; ks < 2; ks++)
        aA[mi][ks] = *(const bf16x8*)&lA[((mi * 16 + lm) * 64 + ks * 32 + q * 8) ^ axor];
#pragma unroll
    for (int nn = 0; nn < 2; nn++)
#pragma unroll
      for (int ks = 0; ks < 2; ks++)
        b0[nn][ks] = *(const bf16x8*)&lB[((rB0 + nn * 16 + lm) * 64 + ks * 32 + q * 8) ^ axor];
    if (j + 2 < NT) STAGE(j + 2, 0, 1);
    SB; LGKM0;
    __builtin_amdgcn_s_setprio(1);
#pragma unroll
    for (int mi = 0; mi < 4; mi++)
#pragma unroll
      for (int nn = 0; nn < 2; nn++)
#pragma unroll
        for (int ks = 0; ks < 2; ks++)
          acc[mi][nn] = __builtin_amdgcn_mfma_f32_16x16x32_bf16(aA[mi][ks], b0[nn][ks], acc[mi][nn], 0, 0, 0);
    __builtin_amdgcn_s_setprio(0);
    SB; FENCE;
    // ---------- p2 ----------
#pragma unroll
    for (int mi = 0; mi < 4; mi++)
#pragma unroll
      for (int ks = 0; ks < 2; ks++)
        aB[mi][ks] = *(const bf16x8*)&lA[(((mi + 4) * 16 + lm) * 64 + ks * 32 + q * 8) ^ axor];
    if (j + 2 < NT) STAGE(j + 2, 1, 1);
    SB; LGKM0;
    __builtin_amdgcn_s_setprio(1);
#pragma unroll
    for (int mi = 0; mi < 4; mi++)
#pragma unroll
      for (int nn = 0; nn < 2; nn++)
#pragma unroll
        for (int ks = 0; ks < 2; ks++)
          acc[mi + 4][nn] = __builtin_amdgcn_mfma_f32_16x16x32_bf16(aB[mi][ks], b0[nn][ks], acc[mi + 4][nn], 0, 0, 0);
    __builtin_amdgcn_s_setprio(0);
    SB; FENCE;
    // ---------- p3 ----------
#pragma unroll
    for (int nn = 0; nn < 2; nn++)
#pragma unroll
      for (int ks = 0; ks < 2; ks++)
        b1[nn][ks] = *(const bf16x8*)&lB[((rB0 + (nn + 2) * 16 + lm) * 64 + ks * 32 + q * 8) ^ axor];
    if (j + 2 < NT) STAGE(j + 2, 0, 0);
    SB; LGKM0;
    __builtin_amdgcn_s_setprio(1);
#pragma unroll
    for (int mi = 0; mi < 4; mi++)
#pragma unroll
      for (int nn = 0; nn < 2; nn++)
#pragma unroll
        for (int ks = 0; ks < 2; ks++)
          acc[mi][nn + 2] = __builtin_amdgcn_mfma_f32_16x16x32_bf16(aA[mi][ks], b1[nn][ks], acc[mi][nn + 2], 0, 0, 0);
    __builtin_amdgcn_s_setprio(0);
    SB; FENCE;
    // ---------- p4 (no mid-barrier: no new reads) ----------
    if (j + 2 < NT) STAGE(j + 2, 1, 0);
    __builtin_amdgcn_s_setprio(1);
#pragma unroll
    for (int mi = 0; mi < 4; mi++)
#pragma unroll
      for (int nn = 0; nn < 2; nn++)
#pragma unroll
        for (int ks = 0; ks < 2; ks++)
          acc[mi + 4][nn + 2] = __builtin_amdgcn_mfma_f32_16x16x32_bf16(aB[mi][ks], b1[nn][ks], acc[mi + 4][nn + 2], 0, 0, 0);
    __builtin_amdgcn_s_setprio(0);
    if (j + 2 < NT) { asm volatile("s_waitcnt vmcnt(8)" ::: "memory"); }
    else            { asm volatile("s_waitcnt vmcnt(0)" ::: "memory"); }
    SB; FENCE;
  }

  // ---- epilogue.  D frag layout: row(m)=q*4+r, col(n)=lm  [m89/m91]
#pragma unroll
  for (int mi = 0; mi < 8; mi++)
#pragma unroll
    for (int ni = 0; ni < 4; ni++)
#pragma unroll
      for (int r = 0; r < 4; r++) {
        const int row = m0 + (w >> 2) * 128 + mi * 16 + q * 4 + r;
        const int col = n0 + (w & 3) * 64 + ni * 16 + lm;
        const float v = acc[mi][ni][r];
        if constexpr (MODE == 0) {
          const int hh = row >> 6, dd = row & 63;
          const int bb2 = col >> 9, ss = col & (SEQ - 1);
          ((__bf16*)Cout)[(size_t)hh * (NPH * SEQ) + (size_t)bb2 * (DH * SEQ) +
                          (size_t)dd * SEQ + ss] = (__bf16)v;
        } else if constexpr (MODE == 1) {
          const int bb2 = col >> 6, dd = col & 63;
          const float vv = fmaxf(v + bias[head * DH + dd], 0.f);
          ((__bf16*)Cout)[((size_t)bb2 * SEQ + row) * HID + head * DH + dd] = (__bf16)vv;
        } else {
          ((float*)Cout)[(size_t)row * HID + col] = v + bias[col];
        }
      }
}

extern "C" void kernel_launch(void* const* d_in, const int* in_sizes, int n_in,
                              void* d_out, int out_size, void* d_ws, size_t ws_size,
                              hipStream_t stream) {
  const int*   x   = (const int*)d_in[0];
  const float* we  = (const float*)d_in[1];
  const float* pe  = (const float*)d_in[2];
  const float* te  = (const float*)d_in[3];
  const float* lng = (const float*)d_in[4];
  const float* lnb = (const float*)d_in[5];
  const float* W   = (const float*)d_in[6];   // [12][768][768] fp32
  const float* bb  = (const float*)d_in[7];   // [12][768] fp32
  const float* M   = (const float*)d_in[8];   // [12][12][512][512] fp32
  const float* lw  = (const float*)d_in[9];
  const float* lb  = (const float*)d_in[10];

  // workspace (bf16), ~141 MB total:
  __bf16* Mt  = (__bf16*)d_ws;                            // 12*12*512*512 = 75.5 MB
  __bf16* Wb  = Mt + (size_t)LAYERS * HEADS * SEQ * SEQ;  // 12*768*768    = 14.2 MB
  __bf16* lwb = Wb + (size_t)LAYERS * HID * HID;          // 768*768       = 1.2 MB
  __bf16* hA  = lwb + (size_t)HID * HID;                  // 16384*768     = 25.2 MB
  __bf16* X   = hA + (size_t)TOK * HID;                   // 12*2048*512   = 25.2 MB (per-head [2048][512])
  float* out = (float*)d_out;

  convert_k<<<LAYERS * HID * HID / 1024, 256, 0, stream>>>(W, Wb);
  convert_k<<<HID * HID / 1024, 256, 0, stream>>>(lw, lwb);
  transpose_all_m_k<<<dim3(8, 8, LAYERS * HEADS), 256, 0, stream>>>(M, Mt);
  embed_ln_k<<<TOK, 256, 0, stream>>>(x, we, pe, te, lng, lnb, hA);
  for (int l = 0; l < LAYERS; l++) {
    // dense: A = Wb[l] (m=dout over 768 -> 3 tiles), B = hA (n=tok -> 64 tiles)
    gemm256_k<0><<<dim3(3, 64), 512, 0, stream>>>(Wb + (size_t)l * HID * HID, hA,
                                                  nullptr, X, HID);
    // mix: per head, A = Mt[l][h] (m=t -> 2 tiles), B = X[h] (n=b*64+d -> 8 tiles)
    gemm256_k<1><<<dim3(2, 8, HEADS), 512, 0, stream>>>(Mt + (size_t)l * HEADS * SEQ * SEQ, X,
                                                        bb + (size_t)l * HID, hA, SEQ);
  }
  // final: A = hA (m=tok -> 64 tiles), B = lwb (n=dout -> 3 tiles), fp32 out
  gemm256_k<2><<<dim3(64, 3), 512, 0, stream>>>(hA, lwb, lb, out, HID);
}

// Round 4
// 1124.338 us; speedup vs baseline: 1.2495x; 1.0994x over previous
//
#include <hip/hip_runtime.h>
#include <hip/hip_bf16.h>

#define SEQ 512
#define HID 768
#define HEADS 12
#define DH 64
#define LAYERS 12
#define BATCH 32
#define TOK (BATCH*SEQ)   // 16384
#define NPH (BATCH*DH)    // 2048: per-head N dimension of the mix GEMM

typedef __attribute__((ext_vector_type(8))) __bf16 bf16x8;
typedef __attribute__((ext_vector_type(4))) __bf16 bf16x4;
typedef __attribute__((ext_vector_type(4))) float f32x4;

typedef __attribute__((address_space(1))) const void gvoid;
typedef __attribute__((address_space(3))) void svoid;
// async global->LDS, 16B/lane; LDS dest must be wave-uniform base + lane*16 [m97/m104]
__device__ __forceinline__ void async_cp16(const void* g, void* l) {
  __builtin_amdgcn_global_load_lds((gvoid*)g, (svoid*)l, 16, 0, 0);
}

#define SB   __builtin_amdgcn_s_barrier()
#define FENCE asm volatile("" ::: "memory")
#define LGKM0 do { asm volatile("s_waitcnt lgkmcnt(0)" ::: "memory"); \
                   __builtin_amdgcn_sched_barrier(0); } while (0)

// ---------------- fp32 -> bf16 bulk convert (W, last_w) ----------------
__global__ __launch_bounds__(256) void convert_k(
    const float* __restrict__ src, __bf16* __restrict__ dst) {
  int i = (blockIdx.x * 256 + threadIdx.x) * 4;
  f32x4 v = *(const f32x4*)&src[i];
  bf16x4 b;
#pragma unroll
  for (int j = 0; j < 4; j++) b[j] = (__bf16)v[j];
  *(bf16x4*)&dst[i] = b;
}

// ---------------- embed + layernorm: fp32 in -> bf16 h[tok][c] ----------------
__global__ __launch_bounds__(256) void embed_ln_k(
    const int* __restrict__ x, const float* __restrict__ we,
    const float* __restrict__ pe, const float* __restrict__ te,
    const float* __restrict__ g, const float* __restrict__ be,
    __bf16* __restrict__ h) {
  const int tok = blockIdx.x;
  const int s = tok & (SEQ - 1);
  const int wid = x[tok];
  const int tid = threadIdx.x;
  float v[3];
  float sum = 0.f, sq = 0.f;
#pragma unroll
  for (int j = 0; j < 3; j++) {
    int c = tid + j * 256;
    float val = we[(size_t)wid * HID + c] + pe[(size_t)s * HID + c] + te[c];
    v[j] = val; sum += val; sq += val * val;
  }
#pragma unroll
  for (int off = 32; off > 0; off >>= 1) {
    sum += __shfl_down(sum, off);
    sq  += __shfl_down(sq, off);
  }
  __shared__ float rs_[4], rq_[4];
  const int wv = tid >> 6;
  if ((tid & 63) == 0) { rs_[wv] = sum; rq_[wv] = sq; }
  __syncthreads();
  sum = rs_[0] + rs_[1] + rs_[2] + rs_[3];
  sq  = rq_[0] + rq_[1] + rq_[2] + rq_[3];
  const float mu  = sum * (1.f / HID);
  const float var = sq * (1.f / HID) - mu * mu;
  const float inv = rsqrtf(var + 1e-12f);
#pragma unroll
  for (int j = 0; j < 3; j++) {
    int c = tid + j * 256;
    float o = (v[j] - mu) * inv * g[c] + be[c];
    h[(size_t)tok * HID + c] = (__bf16)o;
  }
}

// ---------------- all-layer M transpose+convert: Mt[l][h][t][s] = bf16(M[l][h][s][t]) ----------------
__global__ __launch_bounds__(256) void transpose_all_m_k(
    const float* __restrict__ M, __bf16* __restrict__ Mt) {
  __shared__ float tile[64][68];            // +4 pad
  const int lh = blockIdx.z;                // layer*HEADS + head
  const int t0 = blockIdx.x * 64, s0 = blockIdx.y * 64;
  const float* src = M + (size_t)lh * SEQ * SEQ;
  __bf16* dst = Mt + (size_t)lh * SEQ * SEQ;
  const int tid = threadIdx.x;
#pragma unroll
  for (int it = 0; it < 4; it++) {
    int e = (it * 256 + tid) * 4;
    int r = e >> 6, c = e & 63;             // tile[r=s][c=t]
    *(f32x4*)&tile[r][c] = *(const f32x4*)&src[(size_t)(s0 + r) * SEQ + t0 + c];
  }
  __syncthreads();
#pragma unroll
  for (int it = 0; it < 2; it++) {
    int e = (it * 256 + tid) * 8;
    int r = e >> 6, c = e & 63;
    bf16x8 vv;
#pragma unroll
    for (int j = 0; j < 8; j++) vv[j] = (__bf16)tile[c + j][r];
    *(bf16x8*)&dst[(size_t)(t0 + r) * SEQ + s0 + c] = vv;
  }
}

// =====================================================================
// 256x256 / BK=64 8-phase GEMM, round 4: Gray-code quadrants with
// PER-PHASE operand loads (m201-faithful; round-3 held 80+ operand VGPRs
// across phases -> ~240-250 live vs 256 cap -> allocator strangled).
// C[m][n] = sum_k A[m][k] * B[n][k].  8 waves (2Mx4N); wave tile 128x64.
// LDS: A double-buffered (64 KB), B triple-buffered (96 KB) = 160 KB.
// Window j (one K-tile, BK=64), quadrant order A-lo/B-lo -> A-lo/B-hi ->
// A-hi/B-hi -> A-hi/B-lo (B-lo reloaded at p4; one A-half live at a time):
//   p1: read A-lo(8)+B-lo(4) ; stage T(j+2).hB0 ; MFMA acc[0..3][0..1]
//   p2: read B-hi(4)          ; stage T(j+2).hB1 ; MFMA acc[0..3][2..3]
//   p3: read A-hi(8)          ;                    MFMA acc[4..7][2..3]
//   p4: read B-lo(4)          ; stage T(j+2).hA0+hA1 ; MFMA acc[4..7][0..1]
//       vmcnt(8) ; barrier
// Gate vmcnt(8) leaves this window's 8 staged loads in flight, forces
// T(j+1) landed.  Leads: B 7 phases (covers HBM), A 4 phases (A operands
// are L2/L3-resident: Wb/Mt/hA shared across many blocks).
// Restage ledger: B region (j+2)%3==(j-1)%3 last read at j-1 p4, drained
// by its LGKM0 + closing barrier, >=1 barrier before j p1's stage issue.
// A region LA[j&1] last LDS-read at p3 (A-hi), drained by p3's LGKM0;
// p4's stage issues after p3's closing barrier.  Max live operands:
// a(32) + bl(16) + bh(16) transient ~= 48-64 VGPR + acc(128) -> ~210.
// T2 swizzle: linear LDS dest, inverse-swizzled global src col, XOR read.
// MODE 0: dense  -> X[h][b*64+d][s] scatter (bf16)
// MODE 1: mix    -> relu(acc+bias) -> hout[b][t][h*64+d] (bf16)
// MODE 2: final  -> acc+bias -> out[tok][dout] (fp32)
// =====================================================================
template <int MODE>
__global__ __launch_bounds__(512, 2) void gemm256_k(
    const __bf16* __restrict__ Abase, const __bf16* __restrict__ Bbase,
    const float* __restrict__ bias, void* __restrict__ Cout, int K) {
  __shared__ __bf16 LA[2][2][128 * 64];     // 64 KB
  __shared__ __bf16 LB[3][2][128 * 64];     // 96 KB
  const int tid = threadIdx.x;
  const int w = tid >> 6, lane = tid & 63;
  const int lm = lane & 15, q = lane >> 4;
  const int srow = lane >> 3;                                  // staging row within 8-group
  const int scol = ((lane & 7) * 8) ^ ((lane & 32) ? 16 : 0);  // pre-swizzled src col (elems)
  const int axor = (lm & 4) ? 16 : 0;                          // read-side swizzle (elems)
  const int haA = w >> 2;                                      // this wave's A half
  const int hbB = (w & 3) >> 1;                                // this wave's B half
  const int rB0 = (w & 1) * 64;                                // row base within B half
  const int m0 = blockIdx.x * 256, n0 = blockIdx.y * 256;
  const __bf16* A = Abase;
  const __bf16* B = Bbase;
  int head = 0;
  if constexpr (MODE == 1) {
    head = blockIdx.z;
    A += (size_t)head * SEQ * SEQ;
    B += (size_t)head * (NPH * SEQ);
  }

  // stage half-tile (jt, h) of A (isB=0, buffer jt&1) or B (isB=1, buffer jt%3)
  auto STAGE = [&](int jt, int h, int isB) {
    const __bf16* src = isB ? B : A;
    const int r0 = (isB ? n0 : m0) + h * 128 + w * 16 + srow;
    const int kc = jt * 64 + scol;
    __bf16* lds = (isB ? &LB[jt % 3][h][0] : &LA[jt & 1][h][0]) + w * 1024 + lane * 8;
    async_cp16(&src[(size_t)r0 * K + kc], lds);
    async_cp16(&src[(size_t)(r0 + 8) * K + kc], lds + 512);
  };

  f32x4 acc[8][4];
#pragma unroll
  for (int i = 0; i < 8; i++)
#pragma unroll
    for (int j = 0; j < 4; j++) acc[i][j] = {0.f, 0.f, 0.f, 0.f};

  const int NT = K >> 6;
  // ---- prologue: T0 (4 halves) + T1 (4 halves); force T0; barrier
  STAGE(0, 0, 0); STAGE(0, 1, 0); STAGE(0, 0, 1); STAGE(0, 1, 1);
  STAGE(1, 0, 0); STAGE(1, 1, 0); STAGE(1, 0, 1); STAGE(1, 1, 1);
  asm volatile("s_waitcnt vmcnt(8)" ::: "memory");
  SB; FENCE;

  for (int j = 0; j < NT; ++j) {
    const __bf16* lA = &LA[j & 1][haA][0];
    const __bf16* lB = &LB[j % 3][hbB][0];
    bf16x8 a[4][2], bl[2][2], bh[2][2];
    // ---------- p1: read A-lo + B-lo ; stage T(j+2).hB0 ; MFMA Q(lo,lo) ----------
#pragma unroll
    for (int mi = 0; mi < 4; mi++)
#pragma unroll
      for (int ks = 0; ks < 2; ks++)
        a[mi][ks] = *(const bf16x8*)&lA[((mi * 16 + lm) * 64 + ks * 32 + q * 8) ^ axor];
#pragma unroll
    for (int nn = 0; nn < 2; nn++)
#pragma unroll
      for (int ks = 0; ks < 2; ks++)
        bl[nn][ks] = *(const bf16x8*)&lB[((rB0 + nn * 16 + lm) * 64 + ks * 32 + q * 8) ^ axor];
    if (j + 2 < NT) STAGE(j + 2, 0, 1);
    SB; LGKM0;
    __builtin_amdgcn_s_setprio(1);
#pragma unroll
    for (int mi = 0; mi < 4; mi++)
#pragma unroll
      for (int nn = 0; nn < 2; nn++)
#pragma unroll
        for (int ks = 0; ks < 2; ks++)
          acc[mi][nn] = __builtin_amdgcn_mfma_f32_16x16x32_bf16(a[mi][ks], bl[nn][ks], acc[mi][nn], 0, 0, 0);
    __builtin_amdgcn_s_setprio(0);
    SB; FENCE;
    // ---------- p2: read B-hi ; stage T(j+2).hB1 ; MFMA Q(lo,hi) ----------
#pragma unroll
    for (int nn = 0; nn < 2; nn++)
#pragma unroll
      for (int ks = 0; ks < 2; ks++)
        bh[nn][ks] = *(const bf16x8*)&lB[((rB0 + (nn + 2) * 16 + lm) * 64 + ks * 32 + q * 8) ^ axor];
    if (j + 2 < NT) STAGE(j + 2, 1, 1);
    SB; LGKM0;
    __builtin_amdgcn_s_setprio(1);
#pragma unroll
    for (int mi = 0; mi < 4; mi++)
#pragma unroll
      for (int nn = 0; nn < 2; nn++)
#pragma unroll
        for (int ks = 0; ks < 2; ks++)
          acc[mi][nn + 2] = __builtin_amdgcn_mfma_f32_16x16x32_bf16(a[mi][ks], bh[nn][ks], acc[mi][nn + 2], 0, 0, 0);
    __builtin_amdgcn_s_setprio(0);
    SB; FENCE;
    // ---------- p3: read A-hi (overwrites a[]) ; MFMA Q(hi,hi) ----------
#pragma unroll
    for (int mi = 0; mi < 4; mi++)
#pragma unroll
      for (int ks = 0; ks < 2; ks++)
        a[mi][ks] = *(const bf16x8*)&lA[(((mi + 4) * 16 + lm) * 64 + ks * 32 + q * 8) ^ axor];
    SB; LGKM0;
    __builtin_amdgcn_s_setprio(1);
#pragma unroll
    for (int mi = 0; mi < 4; mi++)
#pragma unroll
      for (int nn = 0; nn < 2; nn++)
#pragma unroll
        for (int ks = 0; ks < 2; ks++)
          acc[mi + 4][nn + 2] = __builtin_amdgcn_mfma_f32_16x16x32_bf16(a[mi][ks], bh[nn][ks], acc[mi + 4][nn + 2], 0, 0, 0);
    __builtin_amdgcn_s_setprio(0);
    SB; FENCE;
    // ---------- p4: reload B-lo ; stage T(j+2).hA0+hA1 ; MFMA Q(hi,lo) ----------
#pragma unroll
    for (int nn = 0; nn < 2; nn++)
#pragma unroll
      for (int ks = 0; ks < 2; ks++)
        bl[nn][ks] = *(const bf16x8*)&lB[((rB0 + nn * 16 + lm) * 64 + ks * 32 + q * 8) ^ axor];
    if (j + 2 < NT) { STAGE(j + 2, 0, 0); STAGE(j + 2, 1, 0); }
    SB; LGKM0;
    __builtin_amdgcn_s_setprio(1);
#pragma unroll
    for (int mi = 0; mi < 4; mi++)
#pragma unroll
      for (int nn = 0; nn < 2; nn++)
#pragma unroll
        for (int ks = 0; ks < 2; ks++)
          acc[mi + 4][nn] = __builtin_amdgcn_mfma_f32_16x16x32_bf16(a[mi][ks], bl[nn][ks], acc[mi + 4][nn], 0, 0, 0);
    __builtin_amdgcn_s_setprio(0);
    if (j + 2 < NT) { asm volatile("s_waitcnt vmcnt(8)" ::: "memory"); }
    else            { asm volatile("s_waitcnt vmcnt(0)" ::: "memory"); }
    SB; FENCE;
  }

  // ---- epilogue.  D frag layout: row(m)=q*4+r, col(n)=lm  [m89/m91]
#pragma unroll
  for (int mi = 0; mi < 8; mi++)
#pragma unroll
    for (int ni = 0; ni < 4; ni++)
#pragma unroll
      for (int r = 0; r < 4; r++) {
        const int row = m0 + (w >> 2) * 128 + mi * 16 + q * 4 + r;
        const int col = n0 + (w & 3) * 64 + ni * 16 + lm;
        const float v = acc[mi][ni][r];
        if constexpr (MODE == 0) {
          const int hh = row >> 6, dd = row & 63;
          const int bb2 = col >> 9, ss = col & (SEQ - 1);
          ((__bf16*)Cout)[(size_t)hh * (NPH * SEQ) + (size_t)bb2 * (DH * SEQ) +
                          (size_t)dd * SEQ + ss] = (__bf16)v;
        } else if constexpr (MODE == 1) {
          const int bb2 = col >> 6, dd = col & 63;
          const float vv = fmaxf(v + bias[head * DH + dd], 0.f);
          ((__bf16*)Cout)[((size_t)bb2 * SEQ + row) * HID + head * DH + dd] = (__bf16)vv;
        } else {
          ((float*)Cout)[(size_t)row * HID + col] = v + bias[col];
        }
      }
}

extern "C" void kernel_launch(void* const* d_in, const int* in_sizes, int n_in,
                              void* d_out, int out_size, void* d_ws, size_t ws_size,
                              hipStream_t stream) {
  const int*   x   = (const int*)d_in[0];
  const float* we  = (const float*)d_in[1];
  const float* pe  = (const float*)d_in[2];
  const float* te  = (const float*)d_in[3];
  const float* lng = (const float*)d_in[4];
  const float* lnb = (const float*)d_in[5];
  const float* W   = (const float*)d_in[6];   // [12][768][768] fp32
  const float* bb  = (const float*)d_in[7];   // [12][768] fp32
  const float* M   = (const float*)d_in[8];   // [12][12][512][512] fp32
  const float* lw  = (const float*)d_in[9];
  const float* lb  = (const float*)d_in[10];

  // workspace (bf16), ~141 MB total:
  __bf16* Mt  = (__bf16*)d_ws;                            // 12*12*512*512 = 75.5 MB
  __bf16* Wb  = Mt + (size_t)LAYERS * HEADS * SEQ * SEQ;  // 12*768*768    = 14.2 MB
  __bf16* lwb = Wb + (size_t)LAYERS * HID * HID;          // 768*768       = 1.2 MB
  __bf16* hA  = lwb + (size_t)HID * HID;                  // 16384*768     = 25.2 MB
  __bf16* X   = hA + (size_t)TOK * HID;                   // 12*2048*512   = 25.2 MB (per-head [2048][512])
  float* out = (float*)d_out;

  convert_k<<<LAYERS * HID * HID / 1024, 256, 0, stream>>>(W, Wb);
  convert_k<<<HID * HID / 1024, 256, 0, stream>>>(lw, lwb);
  transpose_all_m_k<<<dim3(8, 8, LAYERS * HEADS), 256, 0, stream>>>(M, Mt);
  embed_ln_k<<<TOK, 256, 0, stream>>>(x, we, pe, te, lng, lnb, hA);
  for (int l = 0; l < LAYERS; l++) {
    // dense: A = Wb[l] (m=dout over 768 -> 3 tiles), B = hA (n=tok -> 64 tiles)
    gemm256_k<0><<<dim3(3, 64), 512, 0, stream>>>(Wb + (size_t)l * HID * HID, hA,
                                                  nullptr, X, HID);
    // mix: per head, A = Mt[l][h] (m=t -> 2 tiles), B = X[h] (n=b*64+d -> 8 tiles)
    gemm256_k<1><<<dim3(2, 8, HEADS), 512, 0, stream>>>(Mt + (size_t)l * HEADS * SEQ * SEQ, X,
                                                        bb + (size_t)l * HID, hA, SEQ);
  }
  // final: A = hA (m=tok -> 64 tiles), B = lwb (n=dout -> 3 tiles), fp32 out
  gemm256_k<2><<<dim3(64, 3), 512, 0, stream>>>(hA, lwb, lb, out, HID);
}